// Round 1
// baseline (228.246 us; speedup 1.0000x reference)
//
#include <hip/hip_runtime.h>
#include <cmath>

#define LOG2E 1.4426950408889634f

typedef __attribute__((ext_vector_type(8))) __bf16 bf16x8;
typedef __attribute__((ext_vector_type(4))) float f32x4;
typedef __attribute__((ext_vector_type(8))) unsigned short ushort8;

__device__ __forceinline__ unsigned short f2bf(float f) {
  unsigned int u = __builtin_bit_cast(unsigned int, f);
  u += 0x7fffu + ((u >> 16) & 1u);   // RNE
  return (unsigned short)(u >> 16);
}

// ---------- kernel 1: Wt[w][n][k] = bf16(W_w[k][n] * (w==0 ? LOG2E/16 : 1)) ----------
__global__ __launch_bounds__(256) void prep_w_kernel(
    const float* __restrict__ Wq, const float* __restrict__ Wk,
    const float* __restrict__ Wv, unsigned short* __restrict__ Wt) {
  const int w = blockIdx.y, n = blockIdx.x, k = threadIdx.x;
  const float* W = (w == 0) ? Wq : ((w == 1) ? Wk : Wv);
  const float s = (w == 0) ? (LOG2E / 16.0f) : 1.0f;
  Wt[w * 65536 + n * 256 + k] = f2bf(W[k * 256 + n] * s);
}

// ---------- kernel 2: q/k/v projection (q,k row-major bf16; v transposed [b][d][s]) ----------
__global__ __launch_bounds__(256) void proj_kernel(
    const float* __restrict__ x, const unsigned short* __restrict__ Wt,
    const float* __restrict__ bq, const float* __restrict__ bk,
    const float* __restrict__ bv,
    unsigned short* __restrict__ q_o, unsigned short* __restrict__ k_o,
    unsigned short* __restrict__ vt_o) {
  const int w = blockIdx.y;            // 0=q 1=k 2=v
  const int mt = blockIdx.x;           // 256 m-tiles of 64 rows
  const int tid = threadIdx.x;
  const int wid = tid >> 6, lane = tid & 63, g = lane >> 4, c = lane & 15;
  const int row_base = mt * 64 + wid * 16;

  // A fragments: x rows (fp32 -> bf16), lane: row = c, k = s*32 + g*8 + j
  bf16x8 a[8];
  const float* xr = x + (size_t)(row_base + c) * 256;
#pragma unroll
  for (int s = 0; s < 8; ++s) {
    const float* p = xr + s * 32 + g * 8;
    union { bf16x8 v; unsigned short u[8]; } t;
#pragma unroll
    for (int j = 0; j < 8; ++j) t.u[j] = f2bf(p[j]);
    a[s] = t.v;
  }

  const float* bias = (w == 0) ? bq : ((w == 1) ? bk : bv);
  const float bscale = (w == 0) ? (LOG2E / 16.0f) : 1.0f;
  const unsigned short* wtb = Wt + w * 65536;

#pragma unroll
  for (int nf = 0; nf < 16; ++nf) {
    f32x4 acc = (f32x4){0.f, 0.f, 0.f, 0.f};
    const unsigned short* wr = wtb + (size_t)(nf * 16 + c) * 256;
#pragma unroll
    for (int s = 0; s < 8; ++s) {
      bf16x8 b = *(const bf16x8*)(wr + s * 32 + g * 8);
      acc = __builtin_amdgcn_mfma_f32_16x16x32_bf16(a[s], b, acc, 0, 0, 0);
    }
    const float bvl = bias[nf * 16 + c] * bscale;
#pragma unroll
    for (int r = 0; r < 4; ++r) {
      const int row = row_base + g * 4 + r;
      const unsigned short ov = f2bf(acc[r] + bvl);
      if (w == 0) {
        q_o[(size_t)row * 256 + nf * 16 + c] = ov;
      } else if (w == 1) {
        k_o[(size_t)row * 256 + nf * 16 + c] = ov;
      } else {
        const int b_ = row >> 12, s_ = row & 4095;
        vt_o[((size_t)b_ * 256 + nf * 16 + c) * 4096 + s_] = ov;
      }
    }
  }
}

// ---------- kernel 3: causal flash attention ----------
// grid 256 = 4 batches x 64 pair-ids; block 256 = 4 waves.
// Block handles q-tiles pi and 127-pi (32 rows each) -> constant 65 kv-steps.
// Waves: wq = wid>>1 (q half), wk = wid&1 (k half for QK^T, d half for PV).
__global__ __launch_bounds__(256) void attn_kernel(
    const unsigned short* __restrict__ qg, const unsigned short* __restrict__ kg,
    const unsigned short* __restrict__ vtg, float* __restrict__ out) {
  __shared__ unsigned short Klds[64 * 256];   // swizzled K tile
  __shared__ unsigned short Vlds[256 * 64];   // swizzled V^T tile
  __shared__ unsigned short Plds[32 * 64];    // swizzled P tile
  __shared__ float smax[2][2][16];
  __shared__ float ssum[2][2][16];

  const int tid = threadIdx.x;
  const int wid = tid >> 6, lane = tid & 63, g = lane >> 4, c = lane & 15;
  const int wq = wid >> 1, wk = wid & 1;
  const int b = blockIdx.x >> 6, pi = blockIdx.x & 63;

  const unsigned short* qb = qg + (size_t)b * 4096 * 256;
  const unsigned short* kb = kg + (size_t)b * 4096 * 256;
  const unsigned short* vb = vtg + (size_t)b * 256 * 4096;
  float* outb = out + (size_t)b * 4096 * 256;

  for (int rep = 0; rep < 2; ++rep) {
    const int qi = rep ? (127 - pi) : pi;
    const int q0 = qi * 32;

    // Q fragments in registers: lane row = c, k = s*32 + g*8 + j
    bf16x8 aq[8];
    {
      const unsigned short* qr = qb + (size_t)(q0 + wq * 16 + c) * 256;
#pragma unroll
      for (int s = 0; s < 8; ++s) aq[s] = *(const bf16x8*)(qr + s * 32 + g * 8);
    }

    float m[4], l[4];
    f32x4 o[8];
#pragma unroll
    for (int r = 0; r < 4; ++r) { m[r] = -INFINITY; l[r] = 0.f; }
#pragma unroll
    for (int fd = 0; fd < 8; ++fd) o[fd] = (f32x4){0.f, 0.f, 0.f, 0.f};

    const int nkv = (qi >> 1) + 1;
    for (int t = 0; t < nkv; ++t) {
      const int kv0 = t * 64;

      // ---- stage K [64][256] and V^T [256][64] into swizzled LDS ----
#pragma unroll
      for (int it = 0; it < 8; ++it) {
        const int slot = it * 256 + tid;
        const int kr = slot >> 5, cs = slot & 31;
        ushort8 v = *(const ushort8*)(kb + (size_t)(kv0 + kr) * 256 + cs * 8);
        *(ushort8*)(Klds + ((kr * 256 + cs * 8) ^ ((kr & 7) << 3))) = v;
      }
#pragma unroll
      for (int it = 0; it < 8; ++it) {
        const int slot = it * 256 + tid;
        const int d = slot >> 3, cs = slot & 7;
        ushort8 v = *(const ushort8*)(vb + (size_t)d * 4096 + kv0 + cs * 8);
        *(ushort8*)(Vlds + ((d * 64 + cs * 8) ^ ((d & 7) << 3))) = v;
      }
      __syncthreads();  // B1: tiles staged

      // ---- QK^T: S[q 16][k 32] for this (wq,wk) quarter ----
      f32x4 sc[2];
      sc[0] = (f32x4){0.f, 0.f, 0.f, 0.f};
      sc[1] = (f32x4){0.f, 0.f, 0.f, 0.f};
#pragma unroll
      for (int f = 0; f < 2; ++f) {
        const int kr = wk * 32 + f * 16 + c;
        const int rowoff = kr * 256, sw = (kr & 7) << 3;
#pragma unroll
        for (int s = 0; s < 8; ++s) {
          bf16x8 bfr = *(const bf16x8*)(Klds + ((rowoff + s * 32 + g * 8) ^ sw));
          sc[f] = __builtin_amdgcn_mfma_f32_16x16x32_bf16(aq[s], bfr, sc[f], 0, 0, 0);
        }
      }

      // ---- mask + per-row partial max (scores already in exp2 domain) ----
      const bool lastt = (t == nkv - 1);
      float pm[4];
#pragma unroll
      for (int r = 0; r < 4; ++r) pm[r] = -INFINITY;
#pragma unroll
      for (int f = 0; f < 2; ++f) {
        const int kcol = kv0 + wk * 32 + f * 16 + c;
#pragma unroll
        for (int r = 0; r < 4; ++r) {
          float v = sc[f][r];
          if (lastt && kcol > q0 + wq * 16 + g * 4 + r) v = -INFINITY;
          sc[f][r] = v;
          pm[r] = fmaxf(pm[r], v);
        }
      }
#pragma unroll
      for (int r = 0; r < 4; ++r) {
        pm[r] = fmaxf(pm[r], __shfl_xor(pm[r], 1));
        pm[r] = fmaxf(pm[r], __shfl_xor(pm[r], 2));
        pm[r] = fmaxf(pm[r], __shfl_xor(pm[r], 4));
        pm[r] = fmaxf(pm[r], __shfl_xor(pm[r], 8));
      }
      if (c == 0) {
#pragma unroll
        for (int r = 0; r < 4; ++r) smax[wq][wk][g * 4 + r] = pm[r];
      }
      __syncthreads();  // B2: partial maxes visible

      // ---- combine max, exp, P write, partial row-sums ----
      float alpha[4], ps[4];
#pragma unroll
      for (int r = 0; r < 4; ++r) {
        const float mn =
            fmaxf(m[r], fmaxf(smax[wq][0][g * 4 + r], smax[wq][1][g * 4 + r]));
        alpha[r] = __builtin_amdgcn_exp2f(m[r] - mn);
        m[r] = mn;
        ps[r] = 0.f;
      }
#pragma unroll
      for (int f = 0; f < 2; ++f) {
        const int kc = wk * 32 + f * 16 + c;
#pragma unroll
        for (int r = 0; r < 4; ++r) {
          const float p = __builtin_amdgcn_exp2f(sc[f][r] - m[r]);
          ps[r] += p;
          const int ql = wq * 16 + g * 4 + r;
          Plds[(ql * 64 + kc) ^ ((ql & 7) << 3)] = f2bf(p);
        }
      }
#pragma unroll
      for (int r = 0; r < 4; ++r) {
        ps[r] += __shfl_xor(ps[r], 1);
        ps[r] += __shfl_xor(ps[r], 2);
        ps[r] += __shfl_xor(ps[r], 4);
        ps[r] += __shfl_xor(ps[r], 8);
      }
      if (c == 0) {
#pragma unroll
        for (int r = 0; r < 4; ++r) ssum[wq][wk][g * 4 + r] = ps[r];
      }
      __syncthreads();  // B3: P tile + partial sums visible

      // ---- l update + O rescale ----
#pragma unroll
      for (int r = 0; r < 4; ++r)
        l[r] = l[r] * alpha[r] + ssum[wq][0][g * 4 + r] + ssum[wq][1][g * 4 + r];
#pragma unroll
      for (int fd = 0; fd < 8; ++fd)
#pragma unroll
        for (int r = 0; r < 4; ++r) o[fd][r] *= alpha[r];

      // ---- PV: O[q 16][d 128-half] += P[q][k64] @ V[k64][d] ----
      bf16x8 pa[2];
      {
        const int ql = wq * 16 + c;
        const int sw = (ql & 7) << 3;
#pragma unroll
        for (int s2 = 0; s2 < 2; ++s2)
          pa[s2] = *(const bf16x8*)(Plds + ((ql * 64 + s2 * 32 + g * 8) ^ sw));
      }
#pragma unroll
      for (int fd = 0; fd < 8; ++fd) {
        const int dl = wk * 128 + fd * 16 + c;
        const int rowoff = dl * 64, sw = (dl & 7) << 3;
#pragma unroll
        for (int s2 = 0; s2 < 2; ++s2) {
          bf16x8 bfr = *(const bf16x8*)(Vlds + ((rowoff + s2 * 32 + g * 8) ^ sw));
          o[fd] = __builtin_amdgcn_mfma_f32_16x16x32_bf16(pa[s2], bfr, o[fd], 0, 0, 0);
        }
      }
      __syncthreads();  // B4: protect LDS before next stage
    }

    // ---- epilogue: O / l -> out (fp32) ----
#pragma unroll
    for (int r = 0; r < 4; ++r) {
      const float inv = 1.0f / l[r];
      const int qrow = q0 + wq * 16 + g * 4 + r;
#pragma unroll
      for (int fd = 0; fd < 8; ++fd) {
        const int dcol = wk * 128 + fd * 16 + c;
        outb[(size_t)qrow * 256 + dcol] = o[fd][r] * inv;
      }
    }
  }
}

extern "C" void kernel_launch(void* const* d_in, const int* in_sizes, int n_in,
                              void* d_out, int out_size, void* d_ws, size_t ws_size,
                              hipStream_t stream) {
  (void)in_sizes; (void)n_in; (void)out_size; (void)ws_size;
  const float* x  = (const float*)d_in[0];
  const float* Wq = (const float*)d_in[1];
  const float* bq = (const float*)d_in[2];
  const float* Wk = (const float*)d_in[3];
  const float* bk = (const float*)d_in[4];
  const float* Wv = (const float*)d_in[5];
  const float* bv = (const float*)d_in[6];
  float* out = (float*)d_out;

  unsigned short* qs  = (unsigned short*)d_ws;                 // [4][4096][256] bf16
  unsigned short* ks  = qs  + (size_t)16384 * 256;             // [4][4096][256] bf16
  unsigned short* vts = ks  + (size_t)16384 * 256;             // [4][256][4096] bf16 (V^T)
  unsigned short* Wt  = vts + (size_t)16384 * 256;             // [3][256][256]  bf16 (W^T)

  prep_w_kernel<<<dim3(256, 3), 256, 0, stream>>>(Wq, Wk, Wv, Wt);
  proj_kernel<<<dim3(256, 3), 256, 0, stream>>>(x, Wt, bq, bk, bv, qs, ks, vts);
  attn_kernel<<<256, 256, 0, stream>>>(qs, ks, vts, out);
}